// Round 4
// baseline (138.172 us; speedup 1.0000x reference)
//
#include <hip/hip_runtime.h>

#define NN 128
#define CC_ 16
#define HH 32
#define WW 32
#define DD 4096   // 16*16*16 pooled features per sample
#define ND (NN*DD)

typedef float v2f __attribute__((ext_vector_type(2)));

// c = sqrt(0.5*log2(e)); folded into the means so the per-term exponent is
// exp2(-(q*q)) with the negate absorbed by the v_exp input modifier.
#define MU_SCALE 0.8493218002880191f

// ---------------------------------------------------------------------------
// Kernel 1: fused 2x2 avg-pool. FLOAT4-interleaved output:
//   wmv[n*DD+d] = {MU_SCALE*ma, MU_SCALE*mb, va, vb}
// Thread 0 zeroes d_out (poisoned 0xAA before every launch).
// ---------------------------------------------------------------------------
__global__ __launch_bounds__(256) void pool_kernel(
    const float* __restrict__ mu_a, const float* __restrict__ lv_a,
    const float* __restrict__ mu_b, const float* __restrict__ lv_b,
    float4* __restrict__ wmv, float* __restrict__ out)
{
    int t = blockIdx.x * 256 + threadIdx.x;
    if (t == 0) out[0] = 0.0f;

    int wo = t & 15;
    int ho = (t >> 4) & 15;
    int c  = (t >> 8) & 15;
    int n  = t >> 12;

    int base = ((n * CC_ + c) * HH + 2 * ho) * WW + 2 * wo;

    float2 a0 = *(const float2*)(mu_a + base);
    float2 a1 = *(const float2*)(mu_a + base + WW);
    float2 la0 = *(const float2*)(lv_a + base);
    float2 la1 = *(const float2*)(lv_a + base + WW);
    float2 b0 = *(const float2*)(mu_b + base);
    float2 b1 = *(const float2*)(mu_b + base + WW);
    float2 lb0 = *(const float2*)(lv_b + base);
    float2 lb1 = *(const float2*)(lv_b + base + WW);

    const float ms = 0.25f * MU_SCALE;
    float ma_v = ms * (a0.x + a0.y + a1.x + a1.y);
    float mb_v = ms * (b0.x + b0.y + b1.x + b1.y);
    float va_v = 0.0625f * (__expf(la0.x) + __expf(la0.y) + __expf(la1.x) + __expf(la1.y));
    float vb_v = 0.0625f * (__expf(lb0.x) + __expf(lb0.y) + __expf(lb1.x) + __expf(lb1.y));

    wmv[t] = make_float4(ma_v, mb_v, va_v, vb_v);
}

// ---------------------------------------------------------------------------
// Kernel 2: triangle-symmetric pair sums.
// R21: R18/R19/R20 falsified trans-pipe, load-pipelining, and load-volume
// theories. Surviving model: DEPENDENCY-LATENCY bound. Issue demand is
// ~42 cy/group (4 trans x 8cy + 5 pk x 2cy) and VALUBusy==54% at 101
// cy/group -> the SIMD idles 46% waiting on serial chains. VGPR_Count=36
// shows the compiler serialized the 12 independent group-chains to save
// registers. This round: PHASE-SEPARATED inner loop (all s/dd, then a burst
// of 12 rsq, then muls, then a burst of 12 exp, then fmas) with static-index
// arrays so the ILP is explicit and register-resident. 4-row tiles to keep
// VGPR ~60-80. One unit/block, 256 units, heavy-first.
// Diagnostic: if VGPR stays <=40 the compiler re-canonicalized -> inline asm.
// ---------------------------------------------------------------------------
__device__ __forceinline__ void pair_group_w(
    v2f& acc, v2f w, v2f mi, v2f mj, v2f vi, v2f vj)
{
    v2f dd = mi - mj;
    v2f s  = vi + vj;
    v2f r;
    r.x = __builtin_amdgcn_rsqf(s.x);
    r.y = __builtin_amdgcn_rsqf(s.y);
    v2f q  = dd * r;
    v2f qq = q * q;
    v2f e;
    e.x = __builtin_amdgcn_exp2f(-qq.x);
    e.y = __builtin_amdgcn_exp2f(-qq.y);
    v2f er = e * r;
    acc += w * er;
}

__device__ __forceinline__ void pair_group(
    v2f& acc, v2f mi, v2f mj, v2f vi, v2f vj)
{
    v2f dd = mi - mj;
    v2f s  = vi + vj;
    v2f r;
    r.x = __builtin_amdgcn_rsqf(s.x);
    r.y = __builtin_amdgcn_rsqf(s.y);
    v2f q  = dd * r;
    v2f qq = q * q;
    v2f e;
    e.x = __builtin_amdgcn_exp2f(-qq.x);
    e.y = __builtin_amdgcn_exp2f(-qq.y);
    acc += e * r;
}

// Phase-separated full work for one j-row: 6 independent v2f-groups
// (12 rsq in one burst, 12 exp in one burst).
__device__ __forceinline__ void do_full_phase(
    float4 jr, v2f& aa, v2f& bb, v2f& ab,
    const v2f pma[2], const v2f pmb[2], const v2f pva[2], const v2f pvb[2])
{
    v2f jma2 = (v2f){jr.x, jr.x};
    v2f jmb2 = (v2f){jr.y, jr.y};
    v2f jva2 = (v2f){jr.z, jr.z};
    v2f jvb2 = (v2f){jr.w, jr.w};

    v2f s[6], dd[6];
    s[0] = pva[0] + jva2;  dd[0] = pma[0] - jma2;   // aa p0
    s[1] = pva[1] + jva2;  dd[1] = pma[1] - jma2;   // aa p1
    s[2] = pvb[0] + jvb2;  dd[2] = pmb[0] - jmb2;   // bb p0
    s[3] = pvb[1] + jvb2;  dd[3] = pmb[1] - jmb2;   // bb p1
    s[4] = pva[0] + jvb2;  dd[4] = pma[0] - jmb2;   // ab p0
    s[5] = pva[1] + jvb2;  dd[5] = pma[1] - jmb2;   // ab p1

    v2f r[6];
#pragma unroll
    for (int k = 0; k < 6; ++k) {
        r[k].x = __builtin_amdgcn_rsqf(s[k].x);
        r[k].y = __builtin_amdgcn_rsqf(s[k].y);
    }
    v2f qq[6];
#pragma unroll
    for (int k = 0; k < 6; ++k) {
        v2f q = dd[k] * r[k];
        qq[k] = q * q;
    }
    v2f e[6];
#pragma unroll
    for (int k = 0; k < 6; ++k) {
        e[k].x = __builtin_amdgcn_exp2f(-qq[k].x);
        e[k].y = __builtin_amdgcn_exp2f(-qq[k].y);
    }
    aa += e[0] * r[0];  aa += e[1] * r[1];
    bb += e[2] * r[2];  bb += e[3] * r[3];
    ab += e[4] * r[4];  ab += e[5] * r[5];
}

// Phase-separated ab-only work for one j-row: 2 independent v2f-groups.
__device__ __forceinline__ void do_ab_phase(
    float4 jr, v2f& ab, const v2f pma[2], const v2f pva[2])
{
    v2f jmb2 = (v2f){jr.y, jr.y};
    v2f jvb2 = (v2f){jr.w, jr.w};

    v2f s[2], dd[2];
    s[0] = pva[0] + jvb2;  dd[0] = pma[0] - jmb2;
    s[1] = pva[1] + jvb2;  dd[1] = pma[1] - jmb2;

    v2f r[2];
#pragma unroll
    for (int k = 0; k < 2; ++k) {
        r[k].x = __builtin_amdgcn_rsqf(s[k].x);
        r[k].y = __builtin_amdgcn_rsqf(s[k].y);
    }
    v2f qq[2];
#pragma unroll
    for (int k = 0; k < 2; ++k) {
        v2f q = dd[k] * r[k];
        qq[k] = q * q;
    }
    v2f e[2];
#pragma unroll
    for (int k = 0; k < 2; ++k) {
        e[k].x = __builtin_amdgcn_exp2f(-qq[k].x);
        e[k].y = __builtin_amdgcn_exp2f(-qq[k].y);
    }
    ab += e[0] * r[0];
    ab += e[1] * r[1];
}

// Process j in [jlo, jhi) against rows i0..i0+3 (3-range triangle split).
// below len = 4*(tile&3), band = 4, above = 12-4*(tile&3) -> all mult. of 4.
__device__ __forceinline__ void run_range4(
    int jlo, int jhi, int i0, int d,
    const float4* __restrict__ wmv,
    v2f& acc_aa, v2f& acc_bb, v2f& acc_ab,
    const v2f pma[2], const v2f pmb[2], const v2f pva[2], const v2f pvb[2])
{
    const int below_end = min(jhi, i0);
    const int band_lo   = max(jlo, i0);
    const int band_hi   = min(jhi, i0 + 4);
    const int above_lo  = max(jlo, i0 + 4);

    // --- below diagonal: full aa + bb + ab ---
#pragma unroll 2
    for (int j = jlo; j < below_end; ++j) {
        float4 jr = wmv[j * DD + d];           // one dwordx4
        do_full_phase(jr, acc_aa, acc_bb, acc_ab, pma, pmb, pva, pvb);
    }

    // --- diagonal band (<=4 iters): per-row half-weights {1, .5, 0} ---
    for (int j = band_lo; j < band_hi; ++j) {
        float4 jr = wmv[j * DD + d];
        v2f jma2 = (v2f){jr.x, jr.x};
        v2f jmb2 = (v2f){jr.y, jr.y};
        v2f jva2 = (v2f){jr.z, jr.z};
        v2f jvb2 = (v2f){jr.w, jr.w};
        v2f w[2];
#pragma unroll
        for (int p = 0; p < 2; ++p) {
            int r0 = i0 + 2 * p, r1 = r0 + 1;
            w[p].x = (j < r0) ? 1.0f : (j == r0 ? 0.5f : 0.0f);
            w[p].y = (j < r1) ? 1.0f : (j == r1 ? 0.5f : 0.0f);
        }
#pragma unroll
        for (int p = 0; p < 2; ++p) {
            pair_group_w(acc_aa, w[p], pma[p], jma2, pva[p], jva2);
            pair_group_w(acc_bb, w[p], pmb[p], jmb2, pvb[p], jvb2);
            pair_group(acc_ab, pma[p], jmb2, pva[p], jvb2);
        }
    }

    // --- above diagonal: ab only ---
#pragma unroll 4
    for (int j = above_lo; j < jhi; ++j) {
        float4 jr = wmv[j * DD + d];
        do_ab_phase(jr, acc_ab, pma, pva);
    }
}

// Load a tile's 4 rows and run one (tile, chunk) unit.
__device__ __forceinline__ void process_unit4(
    int tile, int chunk, int d, const float4* __restrict__ wmv,
    v2f& acc_aa, v2f& acc_bb, v2f& acc_ab)
{
    const int i0 = tile * 4;
    v2f pma[2], pmb[2], pva[2], pvb[2];
#pragma unroll
    for (int p = 0; p < 2; ++p) {
        float4 r0 = wmv[(i0 + 2 * p) * DD + d];
        float4 r1 = wmv[(i0 + 2 * p + 1) * DD + d];
        pma[p] = (v2f){r0.x, r1.x};
        pmb[p] = (v2f){r0.y, r1.y};
        pva[p] = (v2f){r0.z, r1.z};
        pvb[p] = (v2f){r0.w, r1.w};
    }
    run_range4(chunk * 16, chunk * 16 + 16, i0, d, wmv,
               acc_aa, acc_bb, acc_ab, pma, pmb, pva, pvb);
}

// ---------------------------------------------------------------------------
// Unit schedule: 32 tiles (4 rows) x 8 chunks (16 j) = 256 units, one per
// block. g = tile>>2 is the diagonal chunk. Costs (v2f-groups):
//   below-full (c<g): 96 | diag: 48..96 | above ab-only (c>g): 32
// Order y: [0,112) below-full, [112,144) diag, [144,256) above-only.
// Grid = 4096 blocks = 2x wave capacity -> heavy blocks dispatch first,
// light ab-only blocks backfill the drain.
// ---------------------------------------------------------------------------
__device__ __forceinline__ uint2 unit_for(int y) {
    if (y < 112) {           // below-diag full units: tiles 4u..4u+3, u chunks each
        int u, kk;
        if      (y < 4)   { u = 1; kk = y; }
        else if (y < 12)  { u = 2; kk = y - 4; }
        else if (y < 24)  { u = 3; kk = y - 12; }
        else if (y < 40)  { u = 4; kk = y - 24; }
        else if (y < 60)  { u = 5; kk = y - 40; }
        else if (y < 84)  { u = 6; kk = y - 60; }
        else              { u = 7; kk = y - 84; }
        return make_uint2(4 * u + kk / u, kk % u);
    } else if (y < 144) {    // diagonal units
        int t = y - 112;
        return make_uint2(t, t >> 2);
    } else {                 // above-diag ab-only units: tiles 4u..4u+3, 7-u chunks each
        int k = y - 144;
        int u, kk;
        if      (k < 28)  { u = 0; kk = k; }
        else if (k < 52)  { u = 1; kk = k - 28; }
        else if (k < 72)  { u = 2; kk = k - 52; }
        else if (k < 88)  { u = 3; kk = k - 72; }
        else if (k < 100) { u = 4; kk = k - 88; }
        else if (k < 108) { u = 5; kk = k - 100; }
        else              { u = 6; kk = k - 108; }
        int w = 7 - u;
        return make_uint2(4 * u + kk / w, u + 1 + kk % w);
    }
}

__global__ __launch_bounds__(256) void pair_kernel(
    const float4* __restrict__ wmv, float* __restrict__ out)
{
    const int d = blockIdx.x * 256 + threadIdx.x;

    uint2 U = unit_for(blockIdx.y);

    v2f acc_aa = (v2f){0.0f, 0.0f};
    v2f acc_bb = (v2f){0.0f, 0.0f};
    v2f acc_ab = (v2f){0.0f, 0.0f};

    process_unit4((int)U.x, (int)U.y, d, wmv, acc_aa, acc_bb, acc_ab);

    // vaa + vbb - 2 vab = 2 * (half_aa + half_bb - half_ab)
    float part = 2.0f * ((acc_aa.x + acc_aa.y) + (acc_bb.x + acc_bb.y)
                       - (acc_ab.x + acc_ab.y));

    // wave (64-lane) shuffle reduction
#pragma unroll
    for (int off = 32; off > 0; off >>= 1)
        part += __shfl_down(part, off, 64);

    __shared__ float wsum[4];
    int lane = threadIdx.x & 63;
    int wv_  = threadIdx.x >> 6;
    if (lane == 0) wsum[wv_] = part;
    __syncthreads();
    if (threadIdx.x == 0) {
        float s = wsum[0] + wsum[1] + wsum[2] + wsum[3];
        atomicAdd(out, s);
    }
}

extern "C" void kernel_launch(void* const* d_in, const int* in_sizes, int n_in,
                              void* d_out, int out_size, void* d_ws, size_t ws_size,
                              hipStream_t stream) {
    const float* mu_a = (const float*)d_in[0];
    const float* lv_a = (const float*)d_in[1];
    const float* mu_b = (const float*)d_in[2];
    const float* lv_b = (const float*)d_in[3];
    float* out  = (float*)d_out;
    float4* wmv = (float4*)d_ws;           // ND float4 = 8 MB

    pool_kernel<<<dim3(ND / 256), 256, 0, stream>>>(mu_a, lv_a, mu_b, lv_b, wmv, out);
    pair_kernel<<<dim3(DD / 256, 256), 256, 0, stream>>>(wmv, out);
}

// Round 5
// 119.458 us; speedup vs baseline: 1.1567x; 1.1567x over previous
//
#include <hip/hip_runtime.h>

#define NN 128
#define CC_ 16
#define HH 32
#define WW 32
#define DD 4096   // 16*16*16 pooled features per sample
#define ND (NN*DD)

typedef float v2f __attribute__((ext_vector_type(2)));

// c = sqrt(0.5*log2(e)); folded into the means so the per-term exponent is
// exp2(-(q*q)) with the negate absorbed by the v_exp input modifier.
#define MU_SCALE 0.8493218002880191f

// Scheduling fence: VALU may NOT cross; SALU(0x4)+VMEM(0x10)+VMEM_READ(0x20)
// +DS(0x80) may cross (keeps next-j loads pipelined across phases).
#define SBAR() __builtin_amdgcn_sched_barrier(0xB4)

// ---------------------------------------------------------------------------
// Kernel 1: fused 2x2 avg-pool. FLOAT4-interleaved output:
//   wmv[n*DD+d] = {MU_SCALE*ma, MU_SCALE*mb, va, vb}
// Thread 0 zeroes d_out (poisoned 0xAA before every launch).
// ---------------------------------------------------------------------------
__global__ __launch_bounds__(256) void pool_kernel(
    const float* __restrict__ mu_a, const float* __restrict__ lv_a,
    const float* __restrict__ mu_b, const float* __restrict__ lv_b,
    float4* __restrict__ wmv, float* __restrict__ out)
{
    int t = blockIdx.x * 256 + threadIdx.x;
    if (t == 0) out[0] = 0.0f;

    int wo = t & 15;
    int ho = (t >> 4) & 15;
    int c  = (t >> 8) & 15;
    int n  = t >> 12;

    int base = ((n * CC_ + c) * HH + 2 * ho) * WW + 2 * wo;

    float2 a0 = *(const float2*)(mu_a + base);
    float2 a1 = *(const float2*)(mu_a + base + WW);
    float2 la0 = *(const float2*)(lv_a + base);
    float2 la1 = *(const float2*)(lv_a + base + WW);
    float2 b0 = *(const float2*)(mu_b + base);
    float2 b1 = *(const float2*)(mu_b + base + WW);
    float2 lb0 = *(const float2*)(lv_b + base);
    float2 lb1 = *(const float2*)(lv_b + base + WW);

    const float ms = 0.25f * MU_SCALE;
    float ma_v = ms * (a0.x + a0.y + a1.x + a1.y);
    float mb_v = ms * (b0.x + b0.y + b1.x + b1.y);
    float va_v = 0.0625f * (__expf(la0.x) + __expf(la0.y) + __expf(la1.x) + __expf(la1.y));
    float vb_v = 0.0625f * (__expf(lb0.x) + __expf(lb0.y) + __expf(lb1.x) + __expf(lb1.y));

    wmv[t] = make_float4(ma_v, mb_v, va_v, vb_v);
}

// ---------------------------------------------------------------------------
// Kernel 2: triangle-symmetric pair sums.
// R22: R21 proved source-level phase separation is re-canonicalized (VGPR
// stuck at 32). Surviving model: dependency-latency bound (issue demand
// ~42 cy/group, measured 103; VALUBusy 54% == issue port, 46% exposed
// rsq/exp latency). This round: same R20 base (8-row tiles, 128-unit
// heavy-first grid, 2048 blocks -- R19/R21 showed 2x-oversubscribed grids
// cost +20us) but the hot j-iteration is fenced into phases with
// sched_barrier(0xB4): {s,dd} | {12 rsq burst} | {q*q} | {12 exp burst} |
// {fma}. VALU cannot cross the fence -> 12 chains forced live in registers.
// Diagnostic: VGPR must rise to ~80-120; if still ~36 the fence didn't bind.
// ---------------------------------------------------------------------------
__device__ __forceinline__ void pair_group(
    v2f& acc, v2f mi, v2f mj, v2f vi, v2f vj)
{
    v2f dd = mi - mj;          // v_pk_add
    v2f s  = vi + vj;          // v_pk_add
    v2f r;
    r.x = __builtin_amdgcn_rsqf(s.x);
    r.y = __builtin_amdgcn_rsqf(s.y);
    v2f q  = dd * r;           // v_pk_mul
    v2f qq = q * q;            // v_pk_mul
    v2f e;
    e.x = __builtin_amdgcn_exp2f(-qq.x);
    e.y = __builtin_amdgcn_exp2f(-qq.y);
    acc += e * r;              // v_pk_fma
}

__device__ __forceinline__ void pair_group_w(
    v2f& acc, v2f w, v2f mi, v2f mj, v2f vi, v2f vj)
{
    v2f dd = mi - mj;
    v2f s  = vi + vj;
    v2f r;
    r.x = __builtin_amdgcn_rsqf(s.x);
    r.y = __builtin_amdgcn_rsqf(s.y);
    v2f q  = dd * r;
    v2f qq = q * q;
    v2f e;
    e.x = __builtin_amdgcn_exp2f(-qq.x);
    e.y = __builtin_amdgcn_exp2f(-qq.y);
    v2f er = e * r;
    acc += w * er;
}

// One fenced batch of 6 v2f-groups (12 rsq, 12 exp), for i-rows (p0,p1).
__device__ __forceinline__ void batch6(
    v2f& aa, v2f& bb, v2f& ab,
    v2f ma0, v2f ma1, v2f mb0, v2f mb1,
    v2f va0, v2f va1, v2f vb0, v2f vb1,
    v2f jma2, v2f jmb2, v2f jva2, v2f jvb2)
{
    v2f s0 = va0 + jva2, d0 = ma0 - jma2;   // aa p0
    v2f s1 = va1 + jva2, d1 = ma1 - jma2;   // aa p1
    v2f s2 = vb0 + jvb2, d2 = mb0 - jmb2;   // bb p0
    v2f s3 = vb1 + jvb2, d3 = mb1 - jmb2;   // bb p1
    v2f s4 = va0 + jvb2, d4 = ma0 - jmb2;   // ab p0
    v2f s5 = va1 + jvb2, d5 = ma1 - jmb2;   // ab p1
    SBAR();
    v2f r0, r1, r2, r3, r4, r5;
    r0.x = __builtin_amdgcn_rsqf(s0.x); r0.y = __builtin_amdgcn_rsqf(s0.y);
    r1.x = __builtin_amdgcn_rsqf(s1.x); r1.y = __builtin_amdgcn_rsqf(s1.y);
    r2.x = __builtin_amdgcn_rsqf(s2.x); r2.y = __builtin_amdgcn_rsqf(s2.y);
    r3.x = __builtin_amdgcn_rsqf(s3.x); r3.y = __builtin_amdgcn_rsqf(s3.y);
    r4.x = __builtin_amdgcn_rsqf(s4.x); r4.y = __builtin_amdgcn_rsqf(s4.y);
    r5.x = __builtin_amdgcn_rsqf(s5.x); r5.y = __builtin_amdgcn_rsqf(s5.y);
    SBAR();
    v2f q;
    v2f t0, t1, t2, t3, t4, t5;
    q = d0 * r0; t0 = q * q;
    q = d1 * r1; t1 = q * q;
    q = d2 * r2; t2 = q * q;
    q = d3 * r3; t3 = q * q;
    q = d4 * r4; t4 = q * q;
    q = d5 * r5; t5 = q * q;
    SBAR();
    v2f e0, e1, e2, e3, e4, e5;
    e0.x = __builtin_amdgcn_exp2f(-t0.x); e0.y = __builtin_amdgcn_exp2f(-t0.y);
    e1.x = __builtin_amdgcn_exp2f(-t1.x); e1.y = __builtin_amdgcn_exp2f(-t1.y);
    e2.x = __builtin_amdgcn_exp2f(-t2.x); e2.y = __builtin_amdgcn_exp2f(-t2.y);
    e3.x = __builtin_amdgcn_exp2f(-t3.x); e3.y = __builtin_amdgcn_exp2f(-t3.y);
    e4.x = __builtin_amdgcn_exp2f(-t4.x); e4.y = __builtin_amdgcn_exp2f(-t4.y);
    e5.x = __builtin_amdgcn_exp2f(-t5.x); e5.y = __builtin_amdgcn_exp2f(-t5.y);
    SBAR();
    aa += e0 * r0;  aa += e1 * r1;
    bb += e2 * r2;  bb += e3 * r3;
    ab += e4 * r4;  ab += e5 * r5;
    SBAR();
}

// One fenced batch of 4 ab-only v2f-groups (8 rsq, 8 exp), rows p0..p3.
__device__ __forceinline__ void batch4_ab(
    v2f& ab,
    v2f ma0, v2f ma1, v2f ma2, v2f ma3,
    v2f va0, v2f va1, v2f va2, v2f va3,
    v2f jmb2, v2f jvb2)
{
    v2f s0 = va0 + jvb2, d0 = ma0 - jmb2;
    v2f s1 = va1 + jvb2, d1 = ma1 - jmb2;
    v2f s2 = va2 + jvb2, d2 = ma2 - jmb2;
    v2f s3 = va3 + jvb2, d3 = ma3 - jmb2;
    SBAR();
    v2f r0, r1, r2, r3;
    r0.x = __builtin_amdgcn_rsqf(s0.x); r0.y = __builtin_amdgcn_rsqf(s0.y);
    r1.x = __builtin_amdgcn_rsqf(s1.x); r1.y = __builtin_amdgcn_rsqf(s1.y);
    r2.x = __builtin_amdgcn_rsqf(s2.x); r2.y = __builtin_amdgcn_rsqf(s2.y);
    r3.x = __builtin_amdgcn_rsqf(s3.x); r3.y = __builtin_amdgcn_rsqf(s3.y);
    SBAR();
    v2f q;
    v2f t0, t1, t2, t3;
    q = d0 * r0; t0 = q * q;
    q = d1 * r1; t1 = q * q;
    q = d2 * r2; t2 = q * q;
    q = d3 * r3; t3 = q * q;
    SBAR();
    v2f e0, e1, e2, e3;
    e0.x = __builtin_amdgcn_exp2f(-t0.x); e0.y = __builtin_amdgcn_exp2f(-t0.y);
    e1.x = __builtin_amdgcn_exp2f(-t1.x); e1.y = __builtin_amdgcn_exp2f(-t1.y);
    e2.x = __builtin_amdgcn_exp2f(-t2.x); e2.y = __builtin_amdgcn_exp2f(-t2.y);
    e3.x = __builtin_amdgcn_exp2f(-t3.x); e3.y = __builtin_amdgcn_exp2f(-t3.y);
    SBAR();
    ab += e0 * r0;  ab += e1 * r1;  ab += e2 * r2;  ab += e3 * r3;
    SBAR();
}

// Process j in [jlo, jhi) against rows i0..i0+7 (3-range triangle split).
__device__ __forceinline__ void run_range8(
    int jlo, int jhi, int i0, int d,
    const float4* __restrict__ wmv,
    v2f& acc_aa, v2f& acc_bb, v2f& acc_ab,
    const v2f pma[4], const v2f pmb[4], const v2f pva[4], const v2f pvb[4])
{
    const int below_end = min(jhi, i0);
    const int band_lo   = max(jlo, i0);
    const int band_hi   = min(jhi, i0 + 8);
    const int above_lo  = max(jlo, i0 + 8);

    // --- below diagonal: full aa + bb + ab (12 groups per 16B load),
    //     two fenced 6-group batches per j ---
#pragma unroll 2
    for (int j = jlo; j < below_end; ++j) {
        float4 jr = wmv[j * DD + d];           // one dwordx4
        v2f jma2 = (v2f){jr.x, jr.x};
        v2f jmb2 = (v2f){jr.y, jr.y};
        v2f jva2 = (v2f){jr.z, jr.z};
        v2f jvb2 = (v2f){jr.w, jr.w};
        batch6(acc_aa, acc_bb, acc_ab,
               pma[0], pma[1], pmb[0], pmb[1],
               pva[0], pva[1], pvb[0], pvb[1],
               jma2, jmb2, jva2, jvb2);
        batch6(acc_aa, acc_bb, acc_ab,
               pma[2], pma[3], pmb[2], pmb[3],
               pva[2], pva[3], pvb[2], pvb[3],
               jma2, jmb2, jva2, jvb2);
    }

    // --- diagonal band (8 iters): per-row half-weights {1, .5, 0} ---
    for (int j = band_lo; j < band_hi; ++j) {
        float4 jr = wmv[j * DD + d];
        v2f jma2 = (v2f){jr.x, jr.x};
        v2f jmb2 = (v2f){jr.y, jr.y};
        v2f jva2 = (v2f){jr.z, jr.z};
        v2f jvb2 = (v2f){jr.w, jr.w};
        v2f w[4];
#pragma unroll
        for (int p = 0; p < 4; ++p) {
            int r0 = i0 + 2 * p, r1 = r0 + 1;
            w[p].x = (j < r0) ? 1.0f : (j == r0 ? 0.5f : 0.0f);
            w[p].y = (j < r1) ? 1.0f : (j == r1 ? 0.5f : 0.0f);
        }
#pragma unroll
        for (int p = 0; p < 4; ++p) {
            pair_group_w(acc_aa, w[p], pma[p], jma2, pva[p], jva2);
            pair_group_w(acc_bb, w[p], pmb[p], jmb2, pvb[p], jvb2);
            pair_group(acc_ab, pma[p], jmb2, pva[p], jvb2);
        }
    }

    // --- above diagonal: ab only, one fenced 4-group batch per j ---
#pragma unroll 2
    for (int j = above_lo; j < jhi; ++j) {
        float4 jr = wmv[j * DD + d];
        v2f jmb2 = (v2f){jr.y, jr.y};
        v2f jvb2 = (v2f){jr.w, jr.w};
        batch4_ab(acc_ab,
                  pma[0], pma[1], pma[2], pma[3],
                  pva[0], pva[1], pva[2], pva[3],
                  jmb2, jvb2);
    }
}

// Load a tile's 8 rows and run one (tile, chunk) unit.
__device__ __forceinline__ void process_unit8(
    int tile, int chunk, int d, const float4* __restrict__ wmv,
    v2f& acc_aa, v2f& acc_bb, v2f& acc_ab)
{
    const int i0 = tile * 8;
    v2f pma[4], pmb[4], pva[4], pvb[4];
#pragma unroll
    for (int p = 0; p < 4; ++p) {
        float4 r0 = wmv[(i0 + 2 * p) * DD + d];
        float4 r1 = wmv[(i0 + 2 * p + 1) * DD + d];
        pma[p] = (v2f){r0.x, r1.x};
        pmb[p] = (v2f){r0.y, r1.y};
        pva[p] = (v2f){r0.z, r1.z};
        pvb[p] = (v2f){r0.w, r1.w};
    }
    run_range8(chunk * 16, chunk * 16 + 16, i0, d, wmv,
               acc_aa, acc_bb, acc_ab, pma, pmb, pva, pvb);
}

// ---------------------------------------------------------------------------
// Unit schedule (R20's proven best): 16 tiles (8 rows each) x 8 chunks
// (16 j each) = 128 units, 2048 blocks total (exact capacity -- 2x grids
// regressed +20us in R19/R21). Heavy blocks dispatch first.
// ---------------------------------------------------------------------------
__device__ __forceinline__ uint2 unit_for(int y) {
    if (y < 56) {            // below-diag full units (tiles 2u,2u+1, c<u)
        int u, kk;
        if      (y < 2)  { u = 1; kk = y; }
        else if (y < 6)  { u = 2; kk = y - 2; }
        else if (y < 12) { u = 3; kk = y - 6; }
        else if (y < 20) { u = 4; kk = y - 12; }
        else if (y < 30) { u = 5; kk = y - 20; }
        else if (y < 42) { u = 6; kk = y - 30; }
        else             { u = 7; kk = y - 42; }
        return make_uint2(2 * u + kk / u, kk % u);
    } else if (y < 64) {     // odd-tile diagonal
        int u = y - 56;
        return make_uint2(2 * u + 1, u);
    } else if (y < 72) {     // even-tile diagonal
        int u = y - 64;
        return make_uint2(2 * u, u);
    } else {                 // above-diag ab-only (tiles 2u,2u+1, c>u)
        int k = y - 72;
        int u, kk;
        if      (k < 14) { u = 0; kk = k; }
        else if (k < 26) { u = 1; kk = k - 14; }
        else if (k < 36) { u = 2; kk = k - 26; }
        else if (k < 44) { u = 3; kk = k - 36; }
        else if (k < 50) { u = 4; kk = k - 44; }
        else if (k < 54) { u = 5; kk = k - 50; }
        else             { u = 6; kk = k - 54; }
        int w = 7 - u;
        return make_uint2(2 * u + kk / w, u + 1 + kk % w);
    }
}

__global__ __launch_bounds__(256) void pair_kernel(
    const float4* __restrict__ wmv, float* __restrict__ out)
{
    const int d = blockIdx.x * 256 + threadIdx.x;

    uint2 U = unit_for(blockIdx.y);

    v2f acc_aa = (v2f){0.0f, 0.0f};
    v2f acc_bb = (v2f){0.0f, 0.0f};
    v2f acc_ab = (v2f){0.0f, 0.0f};

    process_unit8((int)U.x, (int)U.y, d, wmv, acc_aa, acc_bb, acc_ab);

    // vaa + vbb - 2 vab = 2 * (half_aa + half_bb - half_ab)
    float part = 2.0f * ((acc_aa.x + acc_aa.y) + (acc_bb.x + acc_bb.y)
                       - (acc_ab.x + acc_ab.y));

    // wave (64-lane) shuffle reduction
#pragma unroll
    for (int off = 32; off > 0; off >>= 1)
        part += __shfl_down(part, off, 64);

    __shared__ float wsum[4];
    int lane = threadIdx.x & 63;
    int wv_  = threadIdx.x >> 6;
    if (lane == 0) wsum[wv_] = part;
    __syncthreads();
    if (threadIdx.x == 0) {
        float s = wsum[0] + wsum[1] + wsum[2] + wsum[3];
        atomicAdd(out, s);
    }
}

extern "C" void kernel_launch(void* const* d_in, const int* in_sizes, int n_in,
                              void* d_out, int out_size, void* d_ws, size_t ws_size,
                              hipStream_t stream) {
    const float* mu_a = (const float*)d_in[0];
    const float* lv_a = (const float*)d_in[1];
    const float* mu_b = (const float*)d_in[2];
    const float* lv_b = (const float*)d_in[3];
    float* out  = (float*)d_out;
    float4* wmv = (float4*)d_ws;           // ND float4 = 8 MB

    pool_kernel<<<dim3(ND / 256), 256, 0, stream>>>(mu_a, lv_a, mu_b, lv_b, wmv, out);
    pair_kernel<<<dim3(DD / 256, 128), 256, 0, stream>>>(wmv, out);
}